// Round 16
// baseline (418.870 us; speedup 1.0000x reference)
//
#include <hip/hip_runtime.h>
#include <math.h>

#define NLAYER 4
#define DMODEL 640
#define DINNER 1280
#define DSTATE 16
#define DTRANK 40
#define DCONV  4
#define BATCH  64
#define SEQ    30
#define MTOK   (BATCH*SEQ)       // 1920
#define NPROJ  (2*DINNER)        // 2560
#define NDBL   (DTRANK+2*DSTATE) // 72
#define NDBLP  80                // padded N for x_proj MFMA
#define KSEGS  8
#define KSEG   (DINNER/KSEGS)    // 160
#define DTKP   64                // padded K for dt GEMM

// weight-conversion region sizes (in float4 quads)
#define Q1 (NLAYER*NPROJ*DMODEL/4)   // 1,638,400
#define Q2 (NLAYER*DMODEL*DINNER/4)  //   819,200
#define Q3 (NLAYER*NDBLP*DINNER/4)   //   102,400
#define Q4 (NLAYER*DINNER*DTKP/4)    //    81,920
#define WCTOT (Q1+Q2+Q3+Q4)          // 2,641,920 = 256*10320

typedef unsigned short u16;
typedef __bf16 bf16x8 __attribute__((ext_vector_type(8)));
typedef float  f32x4  __attribute__((ext_vector_type(4)));
typedef unsigned short u16x8 __attribute__((ext_vector_type(8)));

__device__ __forceinline__ float siluf(float x) {
    return x / (1.0f + __expf(-x));
}

__device__ __forceinline__ u16 f2bf(float f) {
    unsigned int u = __float_as_uint(f);
    u += 0x7fffu + ((u >> 16) & 1u);
    return (u16)(u >> 16);
}

__device__ __forceinline__ float bf2f(u16 b) {
    return __uint_as_float(((unsigned int)b) << 16);
}

// h[b,v,:] = x[b,(v + SEQ - vs[b]) % SEQ, :]
__global__ void k_permute(const float* __restrict__ x, const int* __restrict__ vs,
                          float* __restrict__ h) {
    int idx = blockIdx.x * blockDim.x + threadIdx.x;
    if (idx >= MTOK * DMODEL) return;
    int d  = idx % DMODEL;
    int mv = idx / DMODEL;
    int v  = mv % SEQ;
    int b  = mv / SEQ;
    int src = (v + SEQ - vs[b]) % SEQ;
    h[idx] = x[(b * SEQ + src) * DMODEL + d];
}

// single weight-conversion kernel: all bf16 weight buffers in one launch.
__global__ __launch_bounds__(256)
void k_wconv(const float* __restrict__ in_w, const float* __restrict__ out_w,
             const float* __restrict__ xp_w, const float* __restrict__ dt_w,
             u16* __restrict__ wbi, u16* __restrict__ wbo,
             u16* __restrict__ wbx, u16* __restrict__ wdt) {
    int i = blockIdx.x * 256 + threadIdx.x;
    if (i < Q1) {
        int j = i * 4;
        float4 v = *(const float4*)(in_w + j);
        ushort4 o;
        o.x = f2bf(v.x); o.y = f2bf(v.y); o.z = f2bf(v.z); o.w = f2bf(v.w);
        *(ushort4*)(wbi + j) = o;
    } else if (i < Q1 + Q2) {
        int j = (i - Q1) * 4;
        float4 v = *(const float4*)(out_w + j);
        ushort4 o;
        o.x = f2bf(v.x); o.y = f2bf(v.y); o.z = f2bf(v.z); o.w = f2bf(v.w);
        *(ushort4*)(wbo + j) = o;
    } else if (i < Q1 + Q2 + Q3) {
        int j = (i - Q1 - Q2) * 4;
        int layer = j / (NDBLP * DINNER);
        int rem   = j % (NDBLP * DINNER);
        int r = rem / DINNER, c = rem % DINNER;
        ushort4 o = make_ushort4(0, 0, 0, 0);
        if (r < NDBL) {
            float4 v = *(const float4*)(xp_w + ((size_t)layer * NDBL + r) * DINNER + c);
            o.x = f2bf(v.x); o.y = f2bf(v.y); o.z = f2bf(v.z); o.w = f2bf(v.w);
        }
        *(ushort4*)(wbx + j) = o;
    } else {
        int j = (i - Q1 - Q2 - Q3) * 4;
        int ld = j / DTKP;      // layer*1280 + d
        int c  = j % DTKP;
        ushort4 o = make_ushort4(0, 0, 0, 0);
        if (c < DTRANK) {
            float4 v = *(const float4*)(dt_w + (size_t)ld * DTRANK + c);
            o.x = f2bf(v.x); o.y = f2bf(v.y); o.z = f2bf(v.z); o.w = f2bf(v.w);
        }
        *(ushort4*)(wdt + j) = o;
    }
}

// one wave per token: xn_bf16 = h * rsqrt(mean(h^2)+eps) * w  (float2 loads)
__global__ __launch_bounds__(64)
void k_rmsnorm(const float* __restrict__ h, const float* __restrict__ w,
               u16* __restrict__ xn) {
    int m = blockIdx.x;
    int t = threadIdx.x;
    const float* row = h + (size_t)m * DMODEL;
    float2 vv[5];
    float ss = 0.f;
    #pragma unroll
    for (int i = 0; i < 5; ++i) {
        vv[i] = *(const float2*)(row + i * 128 + t * 2);
        ss += vv[i].x * vv[i].x + vv[i].y * vv[i].y;
    }
    #pragma unroll
    for (int o = 32; o > 0; o >>= 1) ss += __shfl_xor(ss, o, 64);
    float sc = rsqrtf(ss / DMODEL + 1e-5f);
    u16* outp = xn + (size_t)m * DMODEL;
    #pragma unroll
    for (int i = 0; i < 5; ++i) {
        int d = i * 128 + t * 2;
        float2 wv = *(const float2*)(w + d);
        ushort2 o;
        o.x = f2bf(vv[i].x * sc * wv.x);
        o.y = f2bf(vv[i].y * sc * wv.y);
        *(ushort2*)(outp + d) = o;
    }
}

// in_proj GEMM: 64x64 tile, 256 thr (4 waves, 32x32 per wave).
// BK=128 (R9-proven pattern): NT=5 drains, 8 loads/thread/stage,
// 16-chunk XOR swizzle. k-ascending order identical to BK=64 version.
// Grid (NPROJ/64=40, MTOK/64=30) = 1200 blocks, LDS 64KB (2 blocks/CU).
__global__ __launch_bounds__(256)
void k_inproj(const u16* __restrict__ A, const u16* __restrict__ W,
              u16* __restrict__ Cb) {
    __shared__ u16 As[2][64 * 128];   // 32KB
    __shared__ u16 Bs[2][64 * 128];   // 32KB
    const int t = threadIdx.x;
    const int w = t >> 6, l = t & 63;
    const int lane15 = l & 15, quad = l >> 4;
    const int wm = w >> 1, wn = w & 1;
    const int m0 = blockIdx.y * 64, n0 = blockIdx.x * 64;

    f32x4 acc[2][2];
    #pragma unroll
    for (int i = 0; i < 2; ++i)
        #pragma unroll
        for (int j = 0; j < 2; ++j)
            acc[i][j] = (f32x4){0.f, 0.f, 0.f, 0.f};

    auto stage = [&](int buf, int k0) {
        #pragma unroll
        for (int q = 0; q < 4; ++q) {        // A: 64 rows x 16 chunks = 1024
            int c   = q * 256 + t;
            int row = c >> 4;
            int gch = ((c & 15) ^ (row & 15)) * 8;
            const u16* ga = A + (size_t)(m0 + row) * DMODEL + k0 + gch;
            __builtin_amdgcn_global_load_lds(
                (const __attribute__((address_space(1))) void*)ga,
                (__attribute__((address_space(3))) void*)&As[buf][c * 8], 16, 0, 0);
        }
        #pragma unroll
        for (int q = 0; q < 4; ++q) {        // B: 64 rows x 16 chunks = 1024
            int c   = q * 256 + t;
            int row = c >> 4;
            int gch = ((c & 15) ^ (row & 15)) * 8;
            const u16* gb = W + (size_t)(n0 + row) * DMODEL + k0 + gch;
            __builtin_amdgcn_global_load_lds(
                (const __attribute__((address_space(1))) void*)gb,
                (__attribute__((address_space(3))) void*)&Bs[buf][c * 8], 16, 0, 0);
        }
    };

    auto compute = [&](int buf) {
        #pragma unroll
        for (int ks = 0; ks < 4; ++ks) {
            bf16x8 af[2], bfr[2];
            #pragma unroll
            for (int i = 0; i < 2; ++i) {
                int row = wm * 32 + i * 16 + lane15;
                af[i] = *(const bf16x8*)&As[buf][row * 128 + (((ks * 4 + quad) ^ (row & 15)) * 8)];
            }
            #pragma unroll
            for (int j = 0; j < 2; ++j) {
                int row = wn * 32 + j * 16 + lane15;
                bfr[j] = *(const bf16x8*)&Bs[buf][row * 128 + (((ks * 4 + quad) ^ (row & 15)) * 8)];
            }
            #pragma unroll
            for (int i = 0; i < 2; ++i)
                #pragma unroll
                for (int j = 0; j < 2; ++j)
                    acc[i][j] = __builtin_amdgcn_mfma_f32_16x16x32_bf16(
                        af[i], bfr[j], acc[i][j], 0, 0, 0);
        }
    };

    const int NT = DMODEL / 128;  // 5
    stage(0, 0);
    __syncthreads();
    int cur = 0;
    for (int tt = 1; tt < NT; ++tt) {
        stage(cur ^ 1, tt * 128);
        compute(cur);
        __syncthreads();
        cur ^= 1;
    }
    compute(cur);

    #pragma unroll
    for (int i = 0; i < 2; ++i) {
        #pragma unroll
        for (int r = 0; r < 4; ++r) {
            int row = m0 + wm * 32 + i * 16 + quad * 4 + r;
            #pragma unroll
            for (int j = 0; j < 2; ++j) {
                int col = n0 + wn * 32 + j * 16 + lane15;
                Cb[(size_t)row * NPROJ + col] = f2bf(acc[i][j][r]);
            }
        }
    }
}

// out_proj GEMM: 32x64 tile, 128 thr (2 waves, 32x32 per wave), f32 out + resid.
// BK=128, NT=10, 16-chunk XOR swizzle. (round-9 proven, best)
__global__ __launch_bounds__(128)
void k_outproj(const u16* __restrict__ A, const u16* __restrict__ W,
               const float* __restrict__ resid, float* __restrict__ C) {
    __shared__ u16 As[2][32 * 128];   // 16KB
    __shared__ u16 Bs[2][64 * 128];   // 32KB
    const int t = threadIdx.x;
    const int w = t >> 6, l = t & 63;
    const int lane15 = l & 15, quad = l >> 4;
    const int m0 = blockIdx.y * 32, n0 = blockIdx.x * 64;

    f32x4 acc[2][2];
    #pragma unroll
    for (int i = 0; i < 2; ++i)
        #pragma unroll
        for (int j = 0; j < 2; ++j)
            acc[i][j] = (f32x4){0.f, 0.f, 0.f, 0.f};

    auto stage = [&](int buf, int k0) {
        #pragma unroll
        for (int q = 0; q < 4; ++q) {        // A: 32 rows x 16 chunks = 512
            int c   = q * 128 + t;
            int row = c >> 4;
            int gch = ((c & 15) ^ (row & 15)) * 8;
            const u16* ga = A + (size_t)(m0 + row) * DINNER + k0 + gch;
            __builtin_amdgcn_global_load_lds(
                (const __attribute__((address_space(1))) void*)ga,
                (__attribute__((address_space(3))) void*)&As[buf][c * 8], 16, 0, 0);
        }
        #pragma unroll
        for (int q = 0; q < 8; ++q) {        // B: 64 rows x 16 chunks = 1024
            int c   = q * 128 + t;
            int row = c >> 4;
            int gch = ((c & 15) ^ (row & 15)) * 8;
            const u16* gb = W + (size_t)(n0 + row) * DINNER + k0 + gch;
            __builtin_amdgcn_global_load_lds(
                (const __attribute__((address_space(1))) void*)gb,
                (__attribute__((address_space(3))) void*)&Bs[buf][c * 8], 16, 0, 0);
        }
    };

    auto compute = [&](int buf) {
        #pragma unroll
        for (int ks = 0; ks < 4; ++ks) {
            bf16x8 af[2], bfr[2];
            #pragma unroll
            for (int i = 0; i < 2; ++i) {
                int row = i * 16 + lane15;
                af[i] = *(const bf16x8*)&As[buf][row * 128 + (((ks * 4 + quad) ^ (row & 15)) * 8)];
            }
            #pragma unroll
            for (int j = 0; j < 2; ++j) {
                int row = w * 32 + j * 16 + lane15;
                bfr[j] = *(const bf16x8*)&Bs[buf][row * 128 + (((ks * 4 + quad) ^ (row & 15)) * 8)];
            }
            #pragma unroll
            for (int i = 0; i < 2; ++i)
                #pragma unroll
                for (int j = 0; j < 2; ++j)
                    acc[i][j] = __builtin_amdgcn_mfma_f32_16x16x32_bf16(
                        af[i], bfr[j], acc[i][j], 0, 0, 0);
        }
    };

    const int NT = DINNER / 128;  // 10
    stage(0, 0);
    __syncthreads();
    int cur = 0;
    for (int tt = 1; tt < NT; ++tt) {
        stage(cur ^ 1, tt * 128);
        compute(cur);
        __syncthreads();
        cur ^= 1;
    }
    compute(cur);

    #pragma unroll
    for (int i = 0; i < 2; ++i) {
        #pragma unroll
        for (int r = 0; r < 4; ++r) {
            int row = m0 + i * 16 + quad * 4 + r;
            #pragma unroll
            for (int j = 0; j < 2; ++j) {
                int col = n0 + w * 32 + j * 16 + lane15;
                size_t idx = (size_t)row * DMODEL + col;
                C[idx] = acc[i][j][r] + resid[idx];
            }
        }
    }
}

// causal depthwise conv + silu, LDS-staged: block = (b, 256-ch chunk).
// urb tile (30 rows x 512B) staged via 960 coalesced 16B gload_lds, one
// drain; serial FIR identical order reads LDS (2-way bank = free).
__global__ __launch_bounds__(256)
void k_conv(const u16* __restrict__ urb, const float* __restrict__ cw,
            const float* __restrict__ cb, u16* __restrict__ ubf) {
    __shared__ u16 UL[SEQ * 256];   // 15KB
    const int t = threadIdx.x;
    const int b  = blockIdx.x / (DINNER / 256);
    const int c0 = (blockIdx.x % (DINNER / 256)) * 256;

    // stage: 30 rows x 32 chunks = 960
    for (int o = t; o < SEQ * 32; o += 256) {
        int v = o >> 5, ch = o & 31;
        const u16* g = urb + (size_t)(b * SEQ + v) * NPROJ + c0 + ch * 8;
        __builtin_amdgcn_global_load_lds(
            (const __attribute__((address_space(1))) void*)g,
            (__attribute__((address_space(3))) void*)&UL[o * 8], 16, 0, 0);
    }
    __syncthreads();

    int c = c0 + t;
    float4 wv = *(const float4*)(cw + c * 4);
    float w0 = wv.x, w1 = wv.y, w2 = wv.z, w3 = wv.w;
    float bias = cb[c];
    u16* op = ubf + (size_t)(b * SEQ) * DINNER + c;
    float x0 = 0.f, x1 = 0.f, x2 = 0.f;
    #pragma unroll
    for (int v = 0; v < SEQ; ++v) {
        float x3 = bf2f(UL[v * 256 + t]);
        float o = bias + w0 * x0 + w1 * x1 + w2 * x2 + w3 * x3;
        op[(size_t)v * DINNER] = f2bf(siluf(o));
        x0 = x1; x1 = x2; x2 = x3;
    }
}

// x_proj: split-K bf16 MFMA, ALL-LOADS-UP-FRONT (R10 proven).
// Grid (KSEGS=8, MTOK/64), 256 thr. Writes fp32 partials dblp[seg][MTOK][80].
__global__ __launch_bounds__(256)
void k_xproj(const u16* __restrict__ ubf, const u16* __restrict__ wbx,
             float* __restrict__ dblp) {
    __shared__ u16 As[64 * KSEG];     // 20KB
    __shared__ u16 Bs[NDBLP * KSEG];  // 25.6KB
    const int t = threadIdx.x;
    const int w = t >> 6, l = t & 63;
    const int lane15 = l & 15, quad = l >> 4;
    const int seg = blockIdx.x;
    const int m0 = blockIdx.y * 64;
    const int kb = seg * KSEG;

    // stage A: 64 rows x 20 chunks = 1280 = 5*256
    #pragma unroll
    for (int q = 0; q < 5; ++q) {
        int c   = q * 256 + t;
        int row = c / 20, ch = c - row * 20;
        const u16* ga = ubf + (size_t)(m0 + row) * DINNER + kb + ch * 8;
        __builtin_amdgcn_global_load_lds(
            (const __attribute__((address_space(1))) void*)ga,
            (__attribute__((address_space(3))) void*)&As[c * 8], 16, 0, 0);
    }
    // stage B: 80 rows x 20 chunks = 1600 = 6*256 + 64
    #pragma unroll
    for (int q = 0; q < 6; ++q) {
        int c   = q * 256 + t;
        int row = c / 20, ch = c - row * 20;
        const u16* gb = wbx + (size_t)row * DINNER + kb + ch * 8;
        __builtin_amdgcn_global_load_lds(
            (const __attribute__((address_space(1))) void*)gb,
            (__attribute__((address_space(3))) void*)&Bs[c * 8], 16, 0, 0);
    }
    if (t < 64) {
        int c   = 1536 + t;
        int row = c / 20, ch = c - row * 20;
        const u16* gb = wbx + (size_t)row * DINNER + kb + ch * 8;
        __builtin_amdgcn_global_load_lds(
            (const __attribute__((address_space(1))) void*)gb,
            (__attribute__((address_space(3))) void*)&Bs[c * 8], 16, 0, 0);
    }
    __syncthreads();   // single drain: all 2880 chunks resident

    f32x4 acc[5];
    #pragma unroll
    for (int j = 0; j < 5; ++j) acc[j] = (f32x4){0.f, 0.f, 0.f, 0.f};

    #pragma unroll
    for (int k0 = 0; k0 < KSEG; k0 += 32) {
        bf16x8 af = *(const bf16x8*)&As[(w * 16 + lane15) * KSEG + k0 + quad * 8];
        #pragma unroll
        for (int j = 0; j < 5; ++j) {
            bf16x8 bfrag = *(const bf16x8*)&Bs[(j * 16 + lane15) * KSEG + k0 + quad * 8];
            acc[j] = __builtin_amdgcn_mfma_f32_16x16x32_bf16(af, bfrag, acc[j], 0, 0, 0);
        }
    }

    float* outp = dblp + (size_t)seg * MTOK * NDBLP;
    #pragma unroll
    for (int r = 0; r < 4; ++r) {
        int row = m0 + w * 16 + quad * 4 + r;
        #pragma unroll
        for (int j = 0; j < 5; ++j) {
            int col = j * 16 + lane15;
            outp[(size_t)row * NDBLP + col] = acc[j][r];
        }
    }
}

// dt prep: hoist the two 20x-redundant dblp reductions out of dtscan.
// dtA[m][64] bf16, bcr[m][32] f32 (identical sg order + rounding).
__global__ __launch_bounds__(256)
void k_dtprep(const float* __restrict__ dblp, u16* __restrict__ dtA,
              float* __restrict__ bcr) {
    int i = blockIdx.x * 256 + threadIdx.x;
    if (i < MTOK * 64) {
        int m = i >> 6, c = i & 63;
        float a = 0.f;
        if (c < DTRANK) {
            #pragma unroll
            for (int sg = 0; sg < KSEGS; ++sg)
                a += dblp[(size_t)sg * MTOK * NDBLP + (size_t)m * NDBLP + c];
        }
        dtA[(size_t)m * 64 + c] = (c < DTRANK) ? f2bf(a) : (u16)0;
    } else {
        int j = i - MTOK * 64;
        int m = j >> 5, s = j & 31;
        float a = 0.f;
        #pragma unroll
        for (int sg = 0; sg < KSEGS; ++sg)
            a += dblp[(size_t)sg * MTOK * NDBLP + (size_t)m * NDBLP + DTRANK + s];
        bcr[(size_t)m * 32 + s] = a;
    }
}

// Fused dt GEMM + softplus + selective scan, v2 (R15 proven, best).
__global__ __launch_bounds__(256)
void k_dtscan(const u16* __restrict__ dtA, const u16* __restrict__ dtwb,
              const float* __restrict__ dtb,
              const u16* __restrict__ ubf, const u16* __restrict__ urb,
              const float* __restrict__ bcr,
              const float* __restrict__ A_log, const float* __restrict__ Dsk,
              u16* __restrict__ y) {
    __shared__ u16 As[64 * 64];         // 8KB
    __shared__ u16 Bs[2][64 * 32];      // 8KB
    __shared__ u16 ldelta[64][64];      // 8KB
    __shared__ float BC2[2][SEQ][32];   // 7.5KB
    __shared__ u16 UU[60 * 64];         // 7.5KB
    __shared__ u16 RR[60 * 64];         // 7.5KB
    const int t = threadIdx.x;
    const int w = t >> 6, l = t & 63;
    const int lane15 = l & 15, quad = l >> 4;
    const int wm = w >> 1, wn = w & 1;
    const int n0 = blockIdx.x * 64;
    const int m0 = blockIdx.y * 60;

    #pragma unroll
    for (int kt = 0; kt < 2; ++kt) {
        int c = t;
        const u16* gb = dtwb + (size_t)(n0 + (c >> 2)) * DTKP + kt * 32 + (c & 3) * 8;
        __builtin_amdgcn_global_load_lds(
            (const __attribute__((address_space(1))) void*)gb,
            (__attribute__((address_space(3))) void*)&Bs[kt][c * 8], 16, 0, 0);
    }
    #pragma unroll
    for (int q = 0; q < 2; ++q) {
        int c = q * 256 + t;
        int row = c >> 3, ch = c & 7;
        int src = min(m0 + row, MTOK - 1);
        const u16* ga = dtA + (size_t)src * 64 + ch * 8;
        __builtin_amdgcn_global_load_lds(
            (const __attribute__((address_space(1))) void*)ga,
            (__attribute__((address_space(3))) void*)&As[c * 8], 16, 0, 0);
    }
    for (int o = t; o < 480; o += 256) {
        const float* g3 = bcr + (size_t)m0 * 32 + o * 4;
        __builtin_amdgcn_global_load_lds(
            (const __attribute__((address_space(1))) void*)g3,
            (__attribute__((address_space(3))) void*)((float*)BC2 + o * 4), 16, 0, 0);
    }
    for (int o = t; o < 480; o += 256) {
        int rr_ = o >> 3, ch = o & 7;
        const u16* g1 = ubf + (size_t)(m0 + rr_) * DINNER + n0 + ch * 8;
        __builtin_amdgcn_global_load_lds(
            (const __attribute__((address_space(1))) void*)g1,
            (__attribute__((address_space(3))) void*)&UU[o * 8], 16, 0, 0);
        const u16* g2 = urb + (size_t)(m0 + rr_) * NPROJ + DINNER + n0 + ch * 8;
        __builtin_amdgcn_global_load_lds(
            (const __attribute__((address_space(1))) void*)g2,
            (__attribute__((address_space(3))) void*)&RR[o * 8], 16, 0, 0);
    }
    __syncthreads();

    f32x4 acc[2][2];
    #pragma unroll
    for (int i = 0; i < 2; ++i)
        #pragma unroll
        for (int j = 0; j < 2; ++j)
            acc[i][j] = (f32x4){0.f, 0.f, 0.f, 0.f};

    #pragma unroll
    for (int kt = 0; kt < 2; ++kt) {
        bf16x8 af[2], bfrag[2];
        #pragma unroll
        for (int i = 0; i < 2; ++i)
            af[i] = *(const bf16x8*)&As[(wm * 32 + i * 16 + lane15) * 64 + kt * 32 + quad * 8];
        #pragma unroll
        for (int j = 0; j < 2; ++j)
            bfrag[j] = *(const bf16x8*)&Bs[kt][(wn * 32 + j * 16 + lane15) * 32 + quad * 8];
        #pragma unroll
        for (int i = 0; i < 2; ++i)
            #pragma unroll
            for (int j = 0; j < 2; ++j)
                acc[i][j] = __builtin_amdgcn_mfma_f32_16x16x32_bf16(
                    af[i], bfrag[j], acc[i][j], 0, 0, 0);
    }

    #pragma unroll
    for (int i = 0; i < 2; ++i) {
        #pragma unroll
        for (int r = 0; r < 4; ++r) {
            int orow = wm * 32 + i * 16 + quad * 4 + r;
            #pragma unroll
            for (int j = 0; j < 2; ++j) {
                int col = wn * 32 + j * 16 + lane15;
                float vv = acc[i][j][r] + dtb[n0 + col];
                vv = (vv > 20.f) ? vv : log1pf(__expf(vv));
                ldelta[orow][col] = f2bf(vv);
            }
        }
    }
    __syncthreads();

    const int lb   = t >> 7;
    const int dloc = (t >> 1) & 63;
    const int half = t & 1;
    const int d    = n0 + dloc;
    const int b    = m0 / SEQ + lb;

    float Ar[8];
    #pragma unroll
    for (int s = 0; s < 8; ++s)
        Ar[s] = -__expf(A_log[(size_t)d * DSTATE + half * 8 + s]);
    float dsk = Dsk[d];
    float st8[8];
    #pragma unroll
    for (int s = 0; s < 8; ++s) st8[s] = 0.f;

    u16* yp = y + (size_t)(b * SEQ) * DINNER + d;

    #pragma unroll
    for (int v = 0; v < SEQ; ++v) {
        float dlt = bf2f(ldelta[lb * SEQ + v][dloc]);
        float u   = bf2f(UU[(lb * SEQ + v) * 64 + dloc]);
        float du  = dlt * u;
        float ya = 0.f, yb = 0.f;
        #pragma unroll
        for (int s = 0; s < 8; s += 4) {
            float dA0 = __expf(dlt * Ar[s + 0]);
            float dA1 = __expf(dlt * Ar[s + 1]);
            float dA2 = __expf(dlt * Ar[s + 2]);
            float dA3 = __expf(dlt * Ar[s + 3]);
            st8[s + 0] = dA0 * st8[s + 0] + du * BC2[lb][v][half * 8 + s + 0];
            st8[s + 1] = dA1 * st8[s + 1] + du * BC2[lb][v][half * 8 + s + 1];
            st8[s + 2] = dA2 * st8[s + 2] + du * BC2[lb][v][half * 8 + s + 2];
            st8[s + 3] = dA3 * st8[s + 3] + du * BC2[lb][v][half * 8 + s + 3];
            ya += st8[s + 0] * BC2[lb][v][DSTATE + half * 8 + s + 0];
            yb += st8[s + 1] * BC2[lb][v][DSTATE + half * 8 + s + 1];
            ya += st8[s + 2] * BC2[lb][v][DSTATE + half * 8 + s + 2];
            yb += st8[s + 3] * BC2[lb][v][DSTATE + half * 8 + s + 3];
        }
        float yh = ya + yb;
        yh += __shfl_xor(yh, 1, 64);
        if (half == 0) {
            float r = bf2f(RR[(lb * SEQ + v) * 64 + dloc]);
            yp[(size_t)v * DINNER] = f2bf((yh + u * dsk) * siluf(r));
        }
    }
}

// final rmsnorm fused with reverse permutation
__global__ __launch_bounds__(64)
void k_final(const float* __restrict__ h, const int* __restrict__ vs,
             const float* __restrict__ w, float* __restrict__ out) {
    int mv = blockIdx.x;
    int v = mv % SEQ, b = mv / SEQ;
    int src = (v + vs[b]) % SEQ;
    const float* row = h + (size_t)(b * SEQ + src) * DMODEL;
    int t = threadIdx.x;
    float ss = 0.f;
    for (int d = t; d < DMODEL; d += 64) { float x = row[d]; ss += x * x; }
    #pragma unroll
    for (int o = 32; o > 0; o >>= 1) ss += __shfl_xor(ss, o, 64);
    float sc = rsqrtf(ss / DMODEL + 1e-5f);
    float* op = out + (size_t)mv * DMODEL;
    for (int d = t; d < DMODEL; d += 64) op[d] = row[d] * sc * w[d];
}

extern "C" void kernel_launch(void* const* d_in, const int* in_sizes, int n_in,
                              void* d_out, int out_size, void* d_ws, size_t ws_size,
                              hipStream_t stream) {
    const float* x      = (const float*)d_in[0];
    const int*   vs     = (const int*)d_in[1];
    const float* norm_w = (const float*)d_in[2];
    const float* in_w   = (const float*)d_in[3];
    const float* conv_w = (const float*)d_in[4];
    const float* conv_b = (const float*)d_in[5];
    const float* xp_w   = (const float*)d_in[6];
    const float* dt_w   = (const float*)d_in[7];
    const float* dt_b   = (const float*)d_in[8];
    const float* A_log  = (const float*)d_in[9];
    const float* Dsk    = (const float*)d_in[10];
    const float* out_w  = (const float*)d_in[11];
    const float* nfw    = (const float*)d_in[12];
    float* out = (float*)d_out;

    char* p = (char*)d_ws;
    float* h      = (float*)p; p += (size_t)MTOK * DMODEL * 4;
    u16*   xn     = (u16*)p;   p += (size_t)MTOK * DMODEL * 2;
    u16*   urb    = (u16*)p;   p += (size_t)MTOK * NPROJ * 2;
    u16*   ubf    = (u16*)p;   p += (size_t)MTOK * DINNER * 2;
    float* dblp   = (float*)p; p += (size_t)KSEGS * MTOK * NDBLP * 4;
    u16*   y      = (u16*)p;   p += (size_t)MTOK * DINNER * 2;
    u16*   dtA    = (u16*)p;   p += (size_t)MTOK * 64 * 2;
    float* bcr    = (float*)p; p += (size_t)MTOK * 32 * 4;
    u16*   wbi4   = (u16*)p;   p += (size_t)NLAYER * NPROJ * DMODEL * 2;
    u16*   wbo4   = (u16*)p;   p += (size_t)NLAYER * DMODEL * DINNER * 2;
    u16*   wbx4   = (u16*)p;   p += (size_t)NLAYER * NDBLP * DINNER * 2;
    u16*   wdt4   = (u16*)p;   p += (size_t)NLAYER * DINNER * DTKP * 2;

    // all weight conversions in one launch
    k_wconv<<<WCTOT / 256, 256, 0, stream>>>(
        in_w, out_w, xp_w, dt_w, wbi4, wbo4, wbx4, wdt4);

    k_permute<<<(MTOK * DMODEL + 255) / 256, 256, 0, stream>>>(x, vs, h);

    for (int l = 0; l < NLAYER; ++l) {
        k_rmsnorm<<<MTOK, 64, 0, stream>>>(h, norm_w + (size_t)l * DMODEL, xn);

        k_inproj<<<dim3(NPROJ / 64, MTOK / 64), 256, 0, stream>>>(
            xn, wbi4 + (size_t)l * NPROJ * DMODEL, urb);

        k_conv<<<BATCH * (DINNER / 256), 256, 0, stream>>>(
            urb, conv_w + (size_t)l * DINNER * DCONV, conv_b + (size_t)l * DINNER, ubf);

        k_xproj<<<dim3(KSEGS, MTOK / 64), 256, 0, stream>>>(
            ubf, wbx4 + (size_t)l * NDBLP * DINNER, dblp);

        k_dtprep<<<(MTOK * 96) / 256, 256, 0, stream>>>(dblp, dtA, bcr);

        k_dtscan<<<dim3(DINNER / 64, MTOK / 60), 256, 0, stream>>>(
            dtA, wdt4 + (size_t)l * DINNER * DTKP, dt_b + (size_t)l * DINNER,
            ubf, urb, bcr,
            A_log + (size_t)l * DINNER * DSTATE, Dsk + (size_t)l * DINNER, y);

        k_outproj<<<dim3(DMODEL / 64, MTOK / 32), 128, 0, stream>>>(
            y, wbo4 + (size_t)l * DMODEL * DINNER, h, h);
    }

    k_final<<<MTOK, 64, 0, stream>>>(h, vs, nfw, out);
}

// Round 17
// 407.628 us; speedup vs baseline: 1.0276x; 1.0276x over previous
//
#include <hip/hip_runtime.h>
#include <math.h>

#define NLAYER 4
#define DMODEL 640
#define DINNER 1280
#define DSTATE 16
#define DTRANK 40
#define DCONV  4
#define BATCH  64
#define SEQ    30
#define MTOK   (BATCH*SEQ)       // 1920
#define NPROJ  (2*DINNER)        // 2560
#define NDBL   (DTRANK+2*DSTATE) // 72
#define NDBLP  80                // padded N for x_proj MFMA
#define KSEGS  8
#define KSEG   (DINNER/KSEGS)    // 160
#define DTKP   64                // padded K for dt GEMM

// weight-conversion region sizes (in float4 quads)
#define Q1 (NLAYER*NPROJ*DMODEL/4)   // 1,638,400
#define Q2 (NLAYER*DMODEL*DINNER/4)  //   819,200
#define Q3 (NLAYER*NDBLP*DINNER/4)   //   102,400
#define Q4 (NLAYER*DINNER*DTKP/4)    //    81,920
#define WCTOT (Q1+Q2+Q3+Q4)          // 2,641,920 = 256*10320

typedef unsigned short u16;
typedef __bf16 bf16x8 __attribute__((ext_vector_type(8)));
typedef float  f32x4  __attribute__((ext_vector_type(4)));
typedef unsigned short u16x8 __attribute__((ext_vector_type(8)));

__device__ __forceinline__ float siluf(float x) {
    return x / (1.0f + __expf(-x));
}

__device__ __forceinline__ u16 f2bf(float f) {
    unsigned int u = __float_as_uint(f);
    u += 0x7fffu + ((u >> 16) & 1u);
    return (u16)(u >> 16);
}

__device__ __forceinline__ float bf2f(u16 b) {
    return __uint_as_float(((unsigned int)b) << 16);
}

// h[b,v,:] = x[b,(v + SEQ - vs[b]) % SEQ, :]
__global__ void k_permute(const float* __restrict__ x, const int* __restrict__ vs,
                          float* __restrict__ h) {
    int idx = blockIdx.x * blockDim.x + threadIdx.x;
    if (idx >= MTOK * DMODEL) return;
    int d  = idx % DMODEL;
    int mv = idx / DMODEL;
    int v  = mv % SEQ;
    int b  = mv / SEQ;
    int src = (v + SEQ - vs[b]) % SEQ;
    h[idx] = x[(b * SEQ + src) * DMODEL + d];
}

// single weight-conversion kernel: all bf16 weight buffers in one launch.
__global__ __launch_bounds__(256)
void k_wconv(const float* __restrict__ in_w, const float* __restrict__ out_w,
             const float* __restrict__ xp_w, const float* __restrict__ dt_w,
             u16* __restrict__ wbi, u16* __restrict__ wbo,
             u16* __restrict__ wbx, u16* __restrict__ wdt) {
    int i = blockIdx.x * 256 + threadIdx.x;
    if (i < Q1) {
        int j = i * 4;
        float4 v = *(const float4*)(in_w + j);
        ushort4 o;
        o.x = f2bf(v.x); o.y = f2bf(v.y); o.z = f2bf(v.z); o.w = f2bf(v.w);
        *(ushort4*)(wbi + j) = o;
    } else if (i < Q1 + Q2) {
        int j = (i - Q1) * 4;
        float4 v = *(const float4*)(out_w + j);
        ushort4 o;
        o.x = f2bf(v.x); o.y = f2bf(v.y); o.z = f2bf(v.z); o.w = f2bf(v.w);
        *(ushort4*)(wbo + j) = o;
    } else if (i < Q1 + Q2 + Q3) {
        int j = (i - Q1 - Q2) * 4;
        int layer = j / (NDBLP * DINNER);
        int rem   = j % (NDBLP * DINNER);
        int r = rem / DINNER, c = rem % DINNER;
        ushort4 o = make_ushort4(0, 0, 0, 0);
        if (r < NDBL) {
            float4 v = *(const float4*)(xp_w + ((size_t)layer * NDBL + r) * DINNER + c);
            o.x = f2bf(v.x); o.y = f2bf(v.y); o.z = f2bf(v.z); o.w = f2bf(v.w);
        }
        *(ushort4*)(wbx + j) = o;
    } else {
        int j = (i - Q1 - Q2 - Q3) * 4;
        int ld = j / DTKP;      // layer*1280 + d
        int c  = j % DTKP;
        ushort4 o = make_ushort4(0, 0, 0, 0);
        if (c < DTRANK) {
            float4 v = *(const float4*)(dt_w + (size_t)ld * DTRANK + c);
            o.x = f2bf(v.x); o.y = f2bf(v.y); o.z = f2bf(v.z); o.w = f2bf(v.w);
        }
        *(ushort4*)(wdt + j) = o;
    }
}

// one wave per token: xn_bf16 = h * rsqrt(mean(h^2)+eps) * w  (float2 loads)
__global__ __launch_bounds__(64)
void k_rmsnorm(const float* __restrict__ h, const float* __restrict__ w,
               u16* __restrict__ xn) {
    int m = blockIdx.x;
    int t = threadIdx.x;
    const float* row = h + (size_t)m * DMODEL;
    float2 vv[5];
    float ss = 0.f;
    #pragma unroll
    for (int i = 0; i < 5; ++i) {
        vv[i] = *(const float2*)(row + i * 128 + t * 2);
        ss += vv[i].x * vv[i].x + vv[i].y * vv[i].y;
    }
    #pragma unroll
    for (int o = 32; o > 0; o >>= 1) ss += __shfl_xor(ss, o, 64);
    float sc = rsqrtf(ss / DMODEL + 1e-5f);
    u16* outp = xn + (size_t)m * DMODEL;
    #pragma unroll
    for (int i = 0; i < 5; ++i) {
        int d = i * 128 + t * 2;
        float2 wv = *(const float2*)(w + d);
        ushort2 o;
        o.x = f2bf(vv[i].x * sc * wv.x);
        o.y = f2bf(vv[i].y * sc * wv.y);
        *(ushort2*)(outp + d) = o;
    }
}

// in_proj GEMM: 64x128 tile, 256 thr (4 waves, 32x64 per wave).
// BK=64, dbuf 2-phase prefetch, XOR chunk swizzle. (R15 proven, best --
// BK=128/64KB-LDS variant regressed via 2 blocks/CU occupancy cliff)
__global__ __launch_bounds__(256)
void k_inproj(const u16* __restrict__ A, const u16* __restrict__ W,
              u16* __restrict__ Cb) {
    __shared__ u16 As[2][64 * 64];
    __shared__ u16 Bs[2][128 * 64];
    const int t = threadIdx.x;
    const int w = t >> 6, l = t & 63;
    const int lane15 = l & 15, quad = l >> 4;
    const int wm = w >> 1, wn = w & 1;   // wm 0..1, wn 0..1
    const int m0 = blockIdx.y * 64, n0 = blockIdx.x * 128;

    f32x4 acc[2][4];
    #pragma unroll
    for (int i = 0; i < 2; ++i)
        #pragma unroll
        for (int j = 0; j < 4; ++j)
            acc[i][j] = (f32x4){0.f, 0.f, 0.f, 0.f};

    auto stage = [&](int buf, int k0) {
        #pragma unroll
        for (int q = 0; q < 2; ++q) {        // A: 64 rows x 8 chunks = 512
            int c   = q * 256 + t;
            int row = c >> 3;
            int gch = ((c & 7) ^ (row & 7)) * 8;
            const u16* ga = A + (size_t)(m0 + row) * DMODEL + k0 + gch;
            __builtin_amdgcn_global_load_lds(
                (const __attribute__((address_space(1))) void*)ga,
                (__attribute__((address_space(3))) void*)&As[buf][c * 8], 16, 0, 0);
        }
        #pragma unroll
        for (int q = 0; q < 4; ++q) {        // B: 128 rows x 8 chunks = 1024
            int c   = q * 256 + t;
            int row = c >> 3;
            int gch = ((c & 7) ^ (row & 7)) * 8;
            const u16* gb = W + (size_t)(n0 + row) * DMODEL + k0 + gch;
            __builtin_amdgcn_global_load_lds(
                (const __attribute__((address_space(1))) void*)gb,
                (__attribute__((address_space(3))) void*)&Bs[buf][c * 8], 16, 0, 0);
        }
    };

    auto compute = [&](int buf) {
        #pragma unroll
        for (int ks = 0; ks < 2; ++ks) {
            bf16x8 af[2], bfr[4];
            #pragma unroll
            for (int i = 0; i < 2; ++i) {
                int row = wm * 32 + i * 16 + lane15;
                af[i] = *(const bf16x8*)&As[buf][row * 64 + (((ks * 4 + quad) ^ (row & 7)) * 8)];
            }
            #pragma unroll
            for (int j = 0; j < 4; ++j) {
                int row = wn * 64 + j * 16 + lane15;
                bfr[j] = *(const bf16x8*)&Bs[buf][row * 64 + (((ks * 4 + quad) ^ (row & 7)) * 8)];
            }
            #pragma unroll
            for (int i = 0; i < 2; ++i)
                #pragma unroll
                for (int j = 0; j < 4; ++j)
                    acc[i][j] = __builtin_amdgcn_mfma_f32_16x16x32_bf16(
                        af[i], bfr[j], acc[i][j], 0, 0, 0);
        }
    };

    const int NT = DMODEL / 64;   // 10
    stage(0, 0);
    __syncthreads();
    int cur = 0;
    for (int tt = 1; tt < NT; ++tt) {
        stage(cur ^ 1, tt * 64);
        compute(cur);
        __syncthreads();
        cur ^= 1;
    }
    compute(cur);

    #pragma unroll
    for (int i = 0; i < 2; ++i) {
        #pragma unroll
        for (int r = 0; r < 4; ++r) {
            int row = m0 + wm * 32 + i * 16 + quad * 4 + r;
            #pragma unroll
            for (int j = 0; j < 4; ++j) {
                int col = n0 + wn * 64 + j * 16 + lane15;
                Cb[(size_t)row * NPROJ + col] = f2bf(acc[i][j][r]);
            }
        }
    }
}

// out_proj GEMM: 32x64 tile, 128 thr (2 waves, 32x32 per wave), f32 out + resid.
// BK=128, NT=10, 16-chunk XOR swizzle. (round-9 proven, best)
__global__ __launch_bounds__(128)
void k_outproj(const u16* __restrict__ A, const u16* __restrict__ W,
               const float* __restrict__ resid, float* __restrict__ C) {
    __shared__ u16 As[2][32 * 128];   // 16KB
    __shared__ u16 Bs[2][64 * 128];   // 32KB
    const int t = threadIdx.x;
    const int w = t >> 6, l = t & 63;
    const int lane15 = l & 15, quad = l >> 4;
    const int m0 = blockIdx.y * 32, n0 = blockIdx.x * 64;

    f32x4 acc[2][2];
    #pragma unroll
    for (int i = 0; i < 2; ++i)
        #pragma unroll
        for (int j = 0; j < 2; ++j)
            acc[i][j] = (f32x4){0.f, 0.f, 0.f, 0.f};

    auto stage = [&](int buf, int k0) {
        #pragma unroll
        for (int q = 0; q < 4; ++q) {        // A: 32 rows x 16 chunks = 512
            int c   = q * 128 + t;
            int row = c >> 4;
            int gch = ((c & 15) ^ (row & 15)) * 8;
            const u16* ga = A + (size_t)(m0 + row) * DINNER + k0 + gch;
            __builtin_amdgcn_global_load_lds(
                (const __attribute__((address_space(1))) void*)ga,
                (__attribute__((address_space(3))) void*)&As[buf][c * 8], 16, 0, 0);
        }
        #pragma unroll
        for (int q = 0; q < 8; ++q) {        // B: 64 rows x 16 chunks = 1024
            int c   = q * 128 + t;
            int row = c >> 4;
            int gch = ((c & 15) ^ (row & 15)) * 8;
            const u16* gb = W + (size_t)(n0 + row) * DINNER + k0 + gch;
            __builtin_amdgcn_global_load_lds(
                (const __attribute__((address_space(1))) void*)gb,
                (__attribute__((address_space(3))) void*)&Bs[buf][c * 8], 16, 0, 0);
        }
    };

    auto compute = [&](int buf) {
        #pragma unroll
        for (int ks = 0; ks < 4; ++ks) {
            bf16x8 af[2], bfr[2];
            #pragma unroll
            for (int i = 0; i < 2; ++i) {
                int row = i * 16 + lane15;
                af[i] = *(const bf16x8*)&As[buf][row * 128 + (((ks * 4 + quad) ^ (row & 15)) * 8)];
            }
            #pragma unroll
            for (int j = 0; j < 2; ++j) {
                int row = w * 32 + j * 16 + lane15;
                bfr[j] = *(const bf16x8*)&Bs[buf][row * 128 + (((ks * 4 + quad) ^ (row & 15)) * 8)];
            }
            #pragma unroll
            for (int i = 0; i < 2; ++i)
                #pragma unroll
                for (int j = 0; j < 2; ++j)
                    acc[i][j] = __builtin_amdgcn_mfma_f32_16x16x32_bf16(
                        af[i], bfr[j], acc[i][j], 0, 0, 0);
        }
    };

    const int NT = DINNER / 128;  // 10
    stage(0, 0);
    __syncthreads();
    int cur = 0;
    for (int tt = 1; tt < NT; ++tt) {
        stage(cur ^ 1, tt * 128);
        compute(cur);
        __syncthreads();
        cur ^= 1;
    }
    compute(cur);

    #pragma unroll
    for (int i = 0; i < 2; ++i) {
        #pragma unroll
        for (int r = 0; r < 4; ++r) {
            int row = m0 + i * 16 + quad * 4 + r;
            #pragma unroll
            for (int j = 0; j < 2; ++j) {
                int col = n0 + w * 32 + j * 16 + lane15;
                size_t idx = (size_t)row * DMODEL + col;
                C[idx] = acc[i][j][r] + resid[idx];
            }
        }
    }
}

// causal depthwise conv + silu, LDS-staged (kept from R16 for clean A/B):
// block = (b, 256-ch chunk); urb tile staged via coalesced 16B gload_lds.
__global__ __launch_bounds__(256)
void k_conv(const u16* __restrict__ urb, const float* __restrict__ cw,
            const float* __restrict__ cb, u16* __restrict__ ubf) {
    __shared__ u16 UL[SEQ * 256];   // 15KB
    const int t = threadIdx.x;
    const int b  = blockIdx.x / (DINNER / 256);
    const int c0 = (blockIdx.x % (DINNER / 256)) * 256;

    // stage: 30 rows x 32 chunks = 960
    for (int o = t; o < SEQ * 32; o += 256) {
        int v = o >> 5, ch = o & 31;
        const u16* g = urb + (size_t)(b * SEQ + v) * NPROJ + c0 + ch * 8;
        __builtin_amdgcn_global_load_lds(
            (const __attribute__((address_space(1))) void*)g,
            (__attribute__((address_space(3))) void*)&UL[o * 8], 16, 0, 0);
    }
    __syncthreads();

    int c = c0 + t;
    float4 wv = *(const float4*)(cw + c * 4);
    float w0 = wv.x, w1 = wv.y, w2 = wv.z, w3 = wv.w;
    float bias = cb[c];
    u16* op = ubf + (size_t)(b * SEQ) * DINNER + c;
    float x0 = 0.f, x1 = 0.f, x2 = 0.f;
    #pragma unroll
    for (int v = 0; v < SEQ; ++v) {
        float x3 = bf2f(UL[v * 256 + t]);
        float o = bias + w0 * x0 + w1 * x1 + w2 * x2 + w3 * x3;
        op[(size_t)v * DINNER] = f2bf(siluf(o));
        x0 = x1; x1 = x2; x2 = x3;
    }
}

// x_proj: split-K bf16 MFMA, ALL-LOADS-UP-FRONT (R10 proven).
// Grid (KSEGS=8, MTOK/64), 256 thr. Writes fp32 partials dblp[seg][MTOK][80].
__global__ __launch_bounds__(256)
void k_xproj(const u16* __restrict__ ubf, const u16* __restrict__ wbx,
             float* __restrict__ dblp) {
    __shared__ u16 As[64 * KSEG];     // 20KB
    __shared__ u16 Bs[NDBLP * KSEG];  // 25.6KB
    const int t = threadIdx.x;
    const int w = t >> 6, l = t & 63;
    const int lane15 = l & 15, quad = l >> 4;
    const int seg = blockIdx.x;
    const int m0 = blockIdx.y * 64;
    const int kb = seg * KSEG;

    // stage A: 64 rows x 20 chunks = 1280 = 5*256
    #pragma unroll
    for (int q = 0; q < 5; ++q) {
        int c   = q * 256 + t;
        int row = c / 20, ch = c - row * 20;
        const u16* ga = ubf + (size_t)(m0 + row) * DINNER + kb + ch * 8;
        __builtin_amdgcn_global_load_lds(
            (const __attribute__((address_space(1))) void*)ga,
            (__attribute__((address_space(3))) void*)&As[c * 8], 16, 0, 0);
    }
    // stage B: 80 rows x 20 chunks = 1600 = 6*256 + 64
    #pragma unroll
    for (int q = 0; q < 6; ++q) {
        int c   = q * 256 + t;
        int row = c / 20, ch = c - row * 20;
        const u16* gb = wbx + (size_t)row * DINNER + kb + ch * 8;
        __builtin_amdgcn_global_load_lds(
            (const __attribute__((address_space(1))) void*)gb,
            (__attribute__((address_space(3))) void*)&Bs[c * 8], 16, 0, 0);
    }
    if (t < 64) {
        int c   = 1536 + t;
        int row = c / 20, ch = c - row * 20;
        const u16* gb = wbx + (size_t)row * DINNER + kb + ch * 8;
        __builtin_amdgcn_global_load_lds(
            (const __attribute__((address_space(1))) void*)gb,
            (__attribute__((address_space(3))) void*)&Bs[c * 8], 16, 0, 0);
    }
    __syncthreads();   // single drain: all 2880 chunks resident

    f32x4 acc[5];
    #pragma unroll
    for (int j = 0; j < 5; ++j) acc[j] = (f32x4){0.f, 0.f, 0.f, 0.f};

    #pragma unroll
    for (int k0 = 0; k0 < KSEG; k0 += 32) {
        bf16x8 af = *(const bf16x8*)&As[(w * 16 + lane15) * KSEG + k0 + quad * 8];
        #pragma unroll
        for (int j = 0; j < 5; ++j) {
            bf16x8 bfrag = *(const bf16x8*)&Bs[(j * 16 + lane15) * KSEG + k0 + quad * 8];
            acc[j] = __builtin_amdgcn_mfma_f32_16x16x32_bf16(af, bfrag, acc[j], 0, 0, 0);
        }
    }

    float* outp = dblp + (size_t)seg * MTOK * NDBLP;
    #pragma unroll
    for (int r = 0; r < 4; ++r) {
        int row = m0 + w * 16 + quad * 4 + r;
        #pragma unroll
        for (int j = 0; j < 5; ++j) {
            int col = j * 16 + lane15;
            outp[(size_t)row * NDBLP + col] = acc[j][r];
        }
    }
}

// dt prep: hoist the two 20x-redundant dblp reductions out of dtscan.
// dtA[m][64] bf16, bcr[m][32] f32 (identical sg order + rounding).
__global__ __launch_bounds__(256)
void k_dtprep(const float* __restrict__ dblp, u16* __restrict__ dtA,
              float* __restrict__ bcr) {
    int i = blockIdx.x * 256 + threadIdx.x;
    if (i < MTOK * 64) {
        int m = i >> 6, c = i & 63;
        float a = 0.f;
        if (c < DTRANK) {
            #pragma unroll
            for (int sg = 0; sg < KSEGS; ++sg)
                a += dblp[(size_t)sg * MTOK * NDBLP + (size_t)m * NDBLP + c];
        }
        dtA[(size_t)m * 64 + c] = (c < DTRANK) ? f2bf(a) : (u16)0;
    } else {
        int j = i - MTOK * 64;
        int m = j >> 5, s = j & 31;
        float a = 0.f;
        #pragma unroll
        for (int sg = 0; sg < KSEGS; ++sg)
            a += dblp[(size_t)sg * MTOK * NDBLP + (size_t)m * NDBLP + DTRANK + s];
        bcr[(size_t)m * 32 + s] = a;
    }
}

// Fused dt GEMM + softplus + selective scan, v2 (R15 proven, best).
__global__ __launch_bounds__(256)
void k_dtscan(const u16* __restrict__ dtA, const u16* __restrict__ dtwb,
              const float* __restrict__ dtb,
              const u16* __restrict__ ubf, const u16* __restrict__ urb,
              const float* __restrict__ bcr,
              const float* __restrict__ A_log, const float* __restrict__ Dsk,
              u16* __restrict__ y) {
    __shared__ u16 As[64 * 64];         // 8KB
    __shared__ u16 Bs[2][64 * 32];      // 8KB
    __shared__ u16 ldelta[64][64];      // 8KB
    __shared__ float BC2[2][SEQ][32];   // 7.5KB
    __shared__ u16 UU[60 * 64];         // 7.5KB
    __shared__ u16 RR[60 * 64];         // 7.5KB
    const int t = threadIdx.x;
    const int w = t >> 6, l = t & 63;
    const int lane15 = l & 15, quad = l >> 4;
    const int wm = w >> 1, wn = w & 1;
    const int n0 = blockIdx.x * 64;
    const int m0 = blockIdx.y * 60;

    #pragma unroll
    for (int kt = 0; kt < 2; ++kt) {
        int c = t;
        const u16* gb = dtwb + (size_t)(n0 + (c >> 2)) * DTKP + kt * 32 + (c & 3) * 8;
        __builtin_amdgcn_global_load_lds(
            (const __attribute__((address_space(1))) void*)gb,
            (__attribute__((address_space(3))) void*)&Bs[kt][c * 8], 16, 0, 0);
    }
    #pragma unroll
    for (int q = 0; q < 2; ++q) {
        int c = q * 256 + t;
        int row = c >> 3, ch = c & 7;
        int src = min(m0 + row, MTOK - 1);
        const u16* ga = dtA + (size_t)src * 64 + ch * 8;
        __builtin_amdgcn_global_load_lds(
            (const __attribute__((address_space(1))) void*)ga,
            (__attribute__((address_space(3))) void*)&As[c * 8], 16, 0, 0);
    }
    for (int o = t; o < 480; o += 256) {
        const float* g3 = bcr + (size_t)m0 * 32 + o * 4;
        __builtin_amdgcn_global_load_lds(
            (const __attribute__((address_space(1))) void*)g3,
            (__attribute__((address_space(3))) void*)((float*)BC2 + o * 4), 16, 0, 0);
    }
    for (int o = t; o < 480; o += 256) {
        int rr_ = o >> 3, ch = o & 7;
        const u16* g1 = ubf + (size_t)(m0 + rr_) * DINNER + n0 + ch * 8;
        __builtin_amdgcn_global_load_lds(
            (const __attribute__((address_space(1))) void*)g1,
            (__attribute__((address_space(3))) void*)&UU[o * 8], 16, 0, 0);
        const u16* g2 = urb + (size_t)(m0 + rr_) * NPROJ + DINNER + n0 + ch * 8;
        __builtin_amdgcn_global_load_lds(
            (const __attribute__((address_space(1))) void*)g2,
            (__attribute__((address_space(3))) void*)&RR[o * 8], 16, 0, 0);
    }
    __syncthreads();

    f32x4 acc[2][2];
    #pragma unroll
    for (int i = 0; i < 2; ++i)
        #pragma unroll
        for (int j = 0; j < 2; ++j)
            acc[i][j] = (f32x4){0.f, 0.f, 0.f, 0.f};

    #pragma unroll
    for (int kt = 0; kt < 2; ++kt) {
        bf16x8 af[2], bfrag[2];
        #pragma unroll
        for (int i = 0; i < 2; ++i)
            af[i] = *(const bf16x8*)&As[(wm * 32 + i * 16 + lane15) * 64 + kt * 32 + quad * 8];
        #pragma unroll
        for (int j = 0; j < 2; ++j)
            bfrag[j] = *(const bf16x8*)&Bs[kt][(wn * 32 + j * 16 + lane15) * 32 + quad * 8];
        #pragma unroll
        for (int i = 0; i < 2; ++i)
            #pragma unroll
            for (int j = 0; j < 2; ++j)
                acc[i][j] = __builtin_amdgcn_mfma_f32_16x16x32_bf16(
                    af[i], bfrag[j], acc[i][j], 0, 0, 0);
    }

    #pragma unroll
    for (int i = 0; i < 2; ++i) {
        #pragma unroll
        for (int r = 0; r < 4; ++r) {
            int orow = wm * 32 + i * 16 + quad * 4 + r;
            #pragma unroll
            for (int j = 0; j < 2; ++j) {
                int col = wn * 32 + j * 16 + lane15;
                float vv = acc[i][j][r] + dtb[n0 + col];
                vv = (vv > 20.f) ? vv : log1pf(__expf(vv));
                ldelta[orow][col] = f2bf(vv);
            }
        }
    }
    __syncthreads();

    const int lb   = t >> 7;
    const int dloc = (t >> 1) & 63;
    const int half = t & 1;
    const int d    = n0 + dloc;
    const int b    = m0 / SEQ + lb;

    float Ar[8];
    #pragma unroll
    for (int s = 0; s < 8; ++s)
        Ar[s] = -__expf(A_log[(size_t)d * DSTATE + half * 8 + s]);
    float dsk = Dsk[d];
    float st8[8];
    #pragma unroll
    for (int s = 0; s < 8; ++s) st8[s] = 0.f;

    u16* yp = y + (size_t)(b * SEQ) * DINNER + d;

    #pragma unroll
    for (int v = 0; v < SEQ; ++v) {
        float dlt = bf2f(ldelta[lb * SEQ + v][dloc]);
        float u   = bf2f(UU[(lb * SEQ + v) * 64 + dloc]);
        float du  = dlt * u;
        float ya = 0.f, yb = 0.f;
        #pragma unroll
        for (int s = 0; s < 8; s += 4) {
            float dA0 = __expf(dlt * Ar[s + 0]);
            float dA1 = __expf(dlt * Ar[s + 1]);
            float dA2 = __expf(dlt * Ar[s + 2]);
            float dA3 = __expf(dlt * Ar[s + 3]);
            st8[s + 0] = dA0 * st8[s + 0] + du * BC2[lb][v][half * 8 + s + 0];
            st8[s + 1] = dA1 * st8[s + 1] + du * BC2[lb][v][half * 8 + s + 1];
            st8[s + 2] = dA2 * st8[s + 2] + du * BC2[lb][v][half * 8 + s + 2];
            st8[s + 3] = dA3 * st8[s + 3] + du * BC2[lb][v][half * 8 + s + 3];
            ya += st8[s + 0] * BC2[lb][v][DSTATE + half * 8 + s + 0];
            yb += st8[s + 1] * BC2[lb][v][DSTATE + half * 8 + s + 1];
            ya += st8[s + 2] * BC2[lb][v][DSTATE + half * 8 + s + 2];
            yb += st8[s + 3] * BC2[lb][v][DSTATE + half * 8 + s + 3];
        }
        float yh = ya + yb;
        yh += __shfl_xor(yh, 1, 64);
        if (half == 0) {
            float r = bf2f(RR[(lb * SEQ + v) * 64 + dloc]);
            yp[(size_t)v * DINNER] = f2bf((yh + u * dsk) * siluf(r));
        }
    }
}

// final rmsnorm fused with reverse permutation
__global__ __launch_bounds__(64)
void k_final(const float* __restrict__ h, const int* __restrict__ vs,
             const float* __restrict__ w, float* __restrict__ out) {
    int mv = blockIdx.x;
    int v = mv % SEQ, b = mv / SEQ;
    int src = (v + vs[b]) % SEQ;
    const float* row = h + (size_t)(b * SEQ + src) * DMODEL;
    int t = threadIdx.x;
    float ss = 0.f;
    for (int d = t; d < DMODEL; d += 64) { float x = row[d]; ss += x * x; }
    #pragma unroll
    for (int o = 32; o > 0; o >>= 1) ss += __shfl_xor(ss, o, 64);
    float sc = rsqrtf(ss / DMODEL + 1e-5f);
    float* op = out + (size_t)mv * DMODEL;
    for (int d = t; d < DMODEL; d += 64) op[d] = row[d] * sc * w[d];
}

extern "C" void kernel_launch(void* const* d_in, const int* in_sizes, int n_in,
                              void* d_out, int out_size, void* d_ws, size_t ws_size,
                              hipStream_t stream) {
    const float* x      = (const float*)d_in[0];
    const int*   vs     = (const int*)d_in[1];
    const float* norm_w = (const float*)d_in[2];
    const float* in_w   = (const float*)d_in[3];
    const float* conv_w = (const float*)d_in[4];
    const float* conv_b = (const float*)d_in[5];
    const float* xp_w   = (const float*)d_in[6];
    const float* dt_w   = (const float*)d_in[7];
    const float* dt_b   = (const float*)d_in[8];
    const float* A_log  = (const float*)d_in[9];
    const float* Dsk    = (const float*)d_in[10];
    const float* out_w  = (const float*)d_in[11];
    const float* nfw    = (const float*)d_in[12];
    float* out = (float*)d_out;

    char* p = (char*)d_ws;
    float* h      = (float*)p; p += (size_t)MTOK * DMODEL * 4;
    u16*   xn     = (u16*)p;   p += (size_t)MTOK * DMODEL * 2;
    u16*   urb    = (u16*)p;   p += (size_t)MTOK * NPROJ * 2;
    u16*   ubf    = (u16*)p;   p += (size_t)MTOK * DINNER * 2;
    float* dblp   = (float*)p; p += (size_t)KSEGS * MTOK * NDBLP * 4;
    u16*   y      = (u16*)p;   p += (size_t)MTOK * DINNER * 2;
    u16*   dtA    = (u16*)p;   p += (size_t)MTOK * 64 * 2;
    float* bcr    = (float*)p; p += (size_t)MTOK * 32 * 4;
    u16*   wbi4   = (u16*)p;   p += (size_t)NLAYER * NPROJ * DMODEL * 2;
    u16*   wbo4   = (u16*)p;   p += (size_t)NLAYER * DMODEL * DINNER * 2;
    u16*   wbx4   = (u16*)p;   p += (size_t)NLAYER * NDBLP * DINNER * 2;
    u16*   wdt4   = (u16*)p;   p += (size_t)NLAYER * DINNER * DTKP * 2;

    // all weight conversions in one launch
    k_wconv<<<WCTOT / 256, 256, 0, stream>>>(
        in_w, out_w, xp_w, dt_w, wbi4, wbo4, wbx4, wdt4);

    k_permute<<<(MTOK * DMODEL + 255) / 256, 256, 0, stream>>>(x, vs, h);

    for (int l = 0; l < NLAYER; ++l) {
        k_rmsnorm<<<MTOK, 64, 0, stream>>>(h, norm_w + (size_t)l * DMODEL, xn);

        k_inproj<<<dim3(NPROJ / 128, MTOK / 64), 256, 0, stream>>>(
            xn, wbi4 + (size_t)l * NPROJ * DMODEL, urb);

        k_conv<<<BATCH * (DINNER / 256), 256, 0, stream>>>(
            urb, conv_w + (size_t)l * DINNER * DCONV, conv_b + (size_t)l * DINNER, ubf);

        k_xproj<<<dim3(KSEGS, MTOK / 64), 256, 0, stream>>>(
            ubf, wbx4 + (size_t)l * NDBLP * DINNER, dblp);

        k_dtprep<<<(MTOK * 96) / 256, 256, 0, stream>>>(dblp, dtA, bcr);

        k_dtscan<<<dim3(DINNER / 64, MTOK / 60), 256, 0, stream>>>(
            dtA, wdt4 + (size_t)l * DINNER * DTKP, dt_b + (size_t)l * DINNER,
            ubf, urb, bcr,
            A_log + (size_t)l * DINNER * DSTATE, Dsk + (size_t)l * DINNER, y);

        k_outproj<<<dim3(DMODEL / 64, MTOK / 32), 128, 0, stream>>>(
            y, wbo4 + (size_t)l * DMODEL * DINNER, h, h);
    }

    k_final<<<MTOK, 64, 0, stream>>>(h, vs, nfw, out);
}